// Round 7
// baseline (95.256 us; speedup 1.0000x reference)
//
#include <hip/hip_runtime.h>
#include <math.h>

#define NPART 2048
#define MI    4               // i-particles per thread (ILP chains)
#define GRPS  8               // wave-groups per block
#define IPB   (GRPS * MI)     // 32 i-particles per block
#define BLOCK 512             // 8 waves; j-split = 64 (full wave)

#if __has_builtin(__builtin_amdgcn_rsqf)
#define RSQF(x) __builtin_amdgcn_rsqf(x)
#else
#define RSQF(x) rsqrtf(x)
#endif
#if __has_builtin(__builtin_amdgcn_exp2f)
#define EXP2F(x) __builtin_amdgcn_exp2f(x)
#else
#define EXP2F(x) exp2f(x)
#endif

// Scaled-coordinate backflow: u = x/L in [0,1).
//   min-image: du -= rint(du)
//   fr = 0.5*(exp2(K * (1/|du|)^5) - 1),  K = -log2(e)*(2.6/L)^5
//   out = L * (u_i + sum_j fr * du)
// Self-pair: d2=0 -> ri=inf -> K*ri^5=-inf -> exp2=0 -> fr=-0.5, fr*0=0. No NaN.
//
// MEASUREMENT ROUND: kernel_launch fires this kernel TWICE (idempotent).
// dur2 = fixed + 2k; prior round gave fixed + k = 73.6 -> k = dur2 - 73.6.
__global__ __launch_bounds__(BLOCK, 4)
void backflow_kernel(const float* __restrict__ x, float* __restrict__ out,
                     float L, float invL, float K) {
    __shared__ float4 ps[NPART];   // 32 KB scaled positions

    const int tid   = threadIdx.x;
    const int blk   = blockIdx.x;
    const int b     = blk >> 6;            // 8 batches x 64 blocks
    const int ibase = (blk & 63) * IPB;
    const float* xb = x + b * (NPART * 3);

    for (int p = tid; p < NPART; p += BLOCK) {
        float ux = xb[3 * p + 0] * invL;
        float uy = xb[3 * p + 1] * invL;
        float uz = xb[3 * p + 2] * invL;
        ux -= floorf(ux);
        uy -= floorf(uy);
        uz -= floorf(uz);
        ps[p] = make_float4(ux, uy, uz, 0.0f);
    }
    __syncthreads();

    const int lane = tid & 63;             // j-split across the full wave
    const int g    = tid >> 6;             // 0..7
    const int i0   = ibase + g * MI;

    float4 pi[MI];
    float  ax[MI], ay[MI], az[MI];
    #pragma unroll
    for (int m = 0; m < MI; ++m) {         // static indices only (no scratch)
        pi[m] = ps[i0 + m];                // wave-uniform broadcast reads
        ax[m] = 0.f; ay[m] = 0.f; az[m] = 0.f;
    }

    #pragma unroll 2
    for (int k = 0; k < NPART / 64; ++k) {
        const float4 pj = ps[lane + (k << 6)];  // contiguous b128, conflict-free
        #pragma unroll
        for (int m = 0; m < MI; ++m) {     // 4 independent chains per b128 read
            float dx = pi[m].x - pj.x, dy = pi[m].y - pj.y, dz = pi[m].z - pj.z;
            dx -= rintf(dx);  dy -= rintf(dy);  dz -= rintf(dz);
            float d2  = fmaf(dx, dx, fmaf(dy, dy, dz * dz));
            float ri  = RSQF(d2);
            float ri2 = ri * ri;
            float ri4 = ri2 * ri2;
            float fr  = fmaf(0.5f, EXP2F((K * ri4) * ri), -0.5f);
            ax[m] = fmaf(fr, dx, ax[m]);
            ay[m] = fmaf(fr, dy, ay[m]);
            az[m] = fmaf(fr, dz, az[m]);
        }
    }

    // full-wave reduction (64 lanes -> lane 0)
    #pragma unroll
    for (int off = 32; off >= 1; off >>= 1) {
        #pragma unroll
        for (int m = 0; m < MI; ++m) {
            ax[m] += __shfl_xor(ax[m], off);
            ay[m] += __shfl_xor(ay[m], off);
            az[m] += __shfl_xor(az[m], off);
        }
    }

    if (lane == 0) {
        float* o = out + (b * NPART + i0) * 3;
        #pragma unroll
        for (int m = 0; m < MI; ++m) {
            o[3 * m + 0] = L * (pi[m].x + ax[m]);
            o[3 * m + 1] = L * (pi[m].y + ay[m]);
            o[3 * m + 2] = L * (pi[m].z + az[m]);
        }
    }
}

extern "C" void kernel_launch(void* const* d_in, const int* in_sizes, int n_in,
                              void* d_out, int out_size, void* d_ws, size_t ws_size,
                              hipStream_t stream) {
    (void)in_sizes; (void)n_in; (void)d_ws; (void)ws_size; (void)out_size;
    const float* x = (const float*)d_in[0];
    float* out     = (float*)d_out;

    const double Ld   = cbrt(2048.0 / 0.016355);
    const double t    = 2.6 / Ld;
    const double Kd   = -(t * t * t * t * t) * 1.4426950408889634;  // -log2(e)*(2.6/L)^5
    const float  L    = (float)Ld;
    const float  invL = (float)(1.0 / Ld);
    const float  K    = (float)Kd;

    const int nblocks = 8 * (NPART / IPB);   // 512 blocks = 2 per CU
    // Launched twice on purpose: dur_us delta vs single-launch round isolates
    // the true kernel duration from the harness's fixed per-replay overhead.
    backflow_kernel<<<nblocks, BLOCK, 0, stream>>>(x, out, L, invL, K);
    backflow_kernel<<<nblocks, BLOCK, 0, stream>>>(x, out, L, invL, K);
}